// Round 1
// baseline (219.990 us; speedup 1.0000x reference)
//
#include <hip/hip_runtime.h>
#include <hip/hip_bf16.h>

#define TTLEN 2048
#define NCH   64
#define CLEN  32    // TTLEN / NCH

typedef unsigned short ushort_t;
typedef __attribute__((ext_vector_type(8))) short short8;
typedef __attribute__((ext_vector_type(4))) float f32x4;

__device__ __forceinline__ unsigned short f2bf(float f) {
    __hip_bfloat16 h = __float2bfloat16(f);
    return *reinterpret_cast<unsigned short*>(&h);
}
__device__ __forceinline__ float bf2f(unsigned int u16) {
    union { unsigned int i; float f; } v; v.i = u16 << 16; return v.f;
}

#define GLD_LDS16(gp, lp) __builtin_amdgcn_global_load_lds( \
    (const __attribute__((address_space(1))) void*)(gp),    \
    (__attribute__((address_space(3))) void*)(lp), 16, 0, 0)

// ---------------- weights fp32 -> bf16, all four in one launch ----------------
__global__ void convert4(const float* __restrict__ Wk, const float* __restrict__ Wv,
                         const float* __restrict__ Wr, const float* __restrict__ Wo,
                         ushort_t* __restrict__ Wall, ushort_t* __restrict__ Wob) {
    int m = blockIdx.x >> 8;                       // 0..3
    const float* src = (m == 0) ? Wk : (m == 1) ? Wv : (m == 2) ? Wr : Wo;
    ushort_t* dst = (m == 3) ? Wob : Wall + (size_t)m * 262144;
    int i = (blockIdx.x & 255) * 256 + threadIdx.x;  // group of 4
    float4 v = *(const float4*)(src + (size_t)i * 4);
    union { unsigned short u[4]; uint2 p; } pk;
    pk.u[0] = f2bf(v.x); pk.u[1] = f2bf(v.y); pk.u[2] = f2bf(v.z); pk.u[3] = f2bf(v.w);
    *(uint2*)(dst + (size_t)i * 4) = pk.p;
}

// ------------- time-shift mix: one x read, three bf16 outputs -------------
__global__ void mix3(const float* __restrict__ x,
                     const float* __restrict__ tmk, const float* __restrict__ tmv,
                     const float* __restrict__ tmr,
                     ushort_t* __restrict__ xk, ushort_t* __restrict__ xv,
                     ushort_t* __restrict__ xr) {
    int i   = blockIdx.x * 256 + threadIdx.x;      // group of 4 channels
    int c4  = (i & 127) << 2;
    int row = i >> 7;                              // b*T + t
    int t   = row & (TTLEN - 1);
    float4 xc = *(const float4*)(x + (size_t)row * 512 + c4);
    float4 xp = make_float4(0.f, 0.f, 0.f, 0.f);
    if (t != 0) xp = *(const float4*)(x + (size_t)(row - 1) * 512 + c4);
    size_t o = (size_t)row * 512 + c4;
    union { unsigned short u[4]; uint2 p; } pk;
    {
        float4 tv = *(const float4*)(tmk + c4);
        pk.u[0] = f2bf(xc.x * tv.x + xp.x * (1.f - tv.x));
        pk.u[1] = f2bf(xc.y * tv.y + xp.y * (1.f - tv.y));
        pk.u[2] = f2bf(xc.z * tv.z + xp.z * (1.f - tv.z));
        pk.u[3] = f2bf(xc.w * tv.w + xp.w * (1.f - tv.w));
        *(uint2*)(xk + o) = pk.p;
    }
    {
        float4 tv = *(const float4*)(tmv + c4);
        pk.u[0] = f2bf(xc.x * tv.x + xp.x * (1.f - tv.x));
        pk.u[1] = f2bf(xc.y * tv.y + xp.y * (1.f - tv.y));
        pk.u[2] = f2bf(xc.z * tv.z + xp.z * (1.f - tv.z));
        pk.u[3] = f2bf(xc.w * tv.w + xp.w * (1.f - tv.w));
        *(uint2*)(xv + o) = pk.p;
    }
    {
        float4 tv = *(const float4*)(tmr + c4);
        pk.u[0] = f2bf(xc.x * tv.x + xp.x * (1.f - tv.x));
        pk.u[1] = f2bf(xc.y * tv.y + xp.y * (1.f - tv.y));
        pk.u[2] = f2bf(xc.z * tv.z + xp.z * (1.f - tv.z));
        pk.u[3] = f2bf(xc.w * tv.w + xp.w * (1.f - tv.w));
        *(uint2*)(xr + o) = pk.p;
    }
}

// ================= 256x256-tile 8-phase GEMM (T2+T3+T4+T5 template) =================
// 512 threads = 8 waves (2M x 4N). Per-wave 128x64 output = acc[8][4] f32x4.
// LDS: 2 buffers x (A 256x64 + B 256x64) bf16 = 128 KiB, chunk-XOR swizzle (16B chunks).
// K = 512 = 8 tiles of BK=64; main loop processes 2 tiles / 8 phases per iteration.
// Phase: {4-12 ds_read_b128 | stage 1 half-tile (2 glb_load_lds x16B) | s_barrier |
//         lgkmcnt(0) | setprio(1) 16 MFMA setprio(0) | [vmcnt(4) @ph4/8] | s_barrier}

// stage one 128-row half-tile (rows relative to src/lds bases), 2 GLDs/thread
__device__ __forceinline__ void stage_half(const ushort_t* src, ushort_t* lds,
                                           int wid, int lane) {
    int ch = lane & 7;
    int r0 = wid * 8 + (lane >> 3);
#pragma unroll
    for (int i = 0; i < 2; ++i) {
        int r = i * 64 + r0;
        // pre-swizzled GLOBAL source chunk, linear LDS dest (rule #21: both-sides)
        GLD_LDS16(src + (size_t)r * 512 + ((ch ^ (r & 7)) << 3),
                  lds + ((i * 64 + wid * 8) << 6));
    }
}

// MODE 0: fused k/v/r (N=1536, A per 512-col band, bf16 out + activations)
// MODE 1: out-projection (N=512, fp32 out, *gamma[t])
template <int MODE>
__launch_bounds__(512, 2)
__global__ void gemm_8ph(const ushort_t* __restrict__ Axk, const ushort_t* __restrict__ Axv,
                         const ushort_t* __restrict__ Axr, const ushort_t* __restrict__ W,
                         const float* __restrict__ b0, const float* __restrict__ b1,
                         const float* __restrict__ b2,
                         ushort_t* __restrict__ o0, ushort_t* __restrict__ o1,
                         ushort_t* __restrict__ o2,
                         float* __restrict__ fout, const float* __restrict__ gamma) {
    __shared__ alignas(16) ushort_t As[2][256 * 64];
    __shared__ alignas(16) ushort_t Bs[2][256 * 64];
    const int tid  = threadIdx.x;
    const int lane = tid & 63;
    const int wid  = tid >> 6;
    const int wm   = (wid >> 2) << 7;   // 0 / 128
    const int wn   = (wid & 3) << 6;    // 0..192
    const int r16  = lane & 15, kq = lane >> 4;
    const int mBlk = blockIdx.x << 8;   // M is the FAST grid dim (A-panel L2 locality)
    const int nBlk = blockIdx.y << 8;
    const int p = nBlk >> 9;            // projection band (MODE 0)
    const ushort_t* Asrc =
        ((MODE == 1) ? Axk : (p == 0 ? Axk : (p == 1 ? Axv : Axr))) + (size_t)mBlk * 512;
    const ushort_t* Bsrc = W + (size_t)nBlk * 512;
    const int swz0 = ((kq ^ (r16 & 7)) << 3);        // k-slice 0 chunk (elements)
    const int swz1 = (((4 + kq) ^ (r16 & 7)) << 3);  // k-slice 1 chunk

    f32x4 acc[8][4];
#pragma unroll
    for (int a = 0; a < 8; ++a)
#pragma unroll
        for (int b = 0; b < 4; ++b) acc[a][b] = (f32x4){0.f, 0.f, 0.f, 0.f};
    short8 bfr[2][4];   // B frags for current tile, live across its 4 phases

#define STAGE_A(buf, tau, h) stage_half(Asrc + (size_t)((h) * 128) * 512 + (tau) * 64, \
                                        &As[buf][(h) * 128 * 64], wid, lane)
#define STAGE_B(buf, tau, h) stage_half(Bsrc + (size_t)((h) * 128) * 512 + (tau) * 64, \
                                        &Bs[buf][(h) * 128 * 64], wid, lane)

    // prologue: tile0 complete + tile1 B halves (3 half-tiles deep max in flight)
    STAGE_B(0, 0, 0); STAGE_B(0, 0, 1); STAGE_A(0, 0, 0); STAGE_A(0, 0, 1);
    STAGE_B(1, 1, 0); STAGE_B(1, 1, 1);
    asm volatile("s_waitcnt vmcnt(4)" ::: "memory");   // tile0 landed, tile1.B in flight
    __builtin_amdgcn_s_barrier();

// VM: 0=none, 1=vmcnt(4) counted, 2=vmcnt(0) (pipeline tail)
#define PHASE(BUF, Q, FIRST, STAGE_STMT, VM) {                                            \
    const ushort_t* Al = &As[BUF][0];                                                     \
    const ushort_t* Bl = &Bs[BUF][0];                                                     \
    short8 af00 = *(const short8*)(Al + ((wm + (2*(Q))*16 + r16) << 6) + swz0);           \
    short8 af10 = *(const short8*)(Al + ((wm + (2*(Q))*16 + r16) << 6) + swz1);           \
    short8 af01 = *(const short8*)(Al + ((wm + (2*(Q)+1)*16 + r16) << 6) + swz0);         \
    short8 af11 = *(const short8*)(Al + ((wm + (2*(Q)+1)*16 + r16) << 6) + swz1);         \
    if (FIRST) {                                                                          \
        _Pragma("unroll")                                                                 \
        for (int n = 0; n < 4; ++n) {                                                     \
            bfr[0][n] = *(const short8*)(Bl + ((wn + n*16 + r16) << 6) + swz0);           \
            bfr[1][n] = *(const short8*)(Bl + ((wn + n*16 + r16) << 6) + swz1);           \
        }                                                                                 \
    }                                                                                     \
    STAGE_STMT;                                                                           \
    __builtin_amdgcn_s_barrier();                                                         \
    asm volatile("s_waitcnt lgkmcnt(0)" ::: "memory");                                    \
    __builtin_amdgcn_sched_barrier(0);                                                    \
    __builtin_amdgcn_s_setprio(1);                                                        \
    _Pragma("unroll")                                                                     \
    for (int n = 0; n < 4; ++n) {                                                         \
        acc[2*(Q)][n]   = __builtin_amdgcn_mfma_f32_16x16x32_bf16(af00, bfr[0][n], acc[2*(Q)][n],   0, 0, 0); \
        acc[2*(Q)+1][n] = __builtin_amdgcn_mfma_f32_16x16x32_bf16(af01, bfr[0][n], acc[2*(Q)+1][n], 0, 0, 0); \
    }                                                                                     \
    _Pragma("unroll")                                                                     \
    for (int n = 0; n < 4; ++n) {                                                         \
        acc[2*(Q)][n]   = __builtin_amdgcn_mfma_f32_16x16x32_bf16(af10, bfr[1][n], acc[2*(Q)][n],   0, 0, 0); \
        acc[2*(Q)+1][n] = __builtin_amdgcn_mfma_f32_16x16x32_bf16(af11, bfr[1][n], acc[2*(Q)+1][n], 0, 0, 0); \
    }                                                                                     \
    __builtin_amdgcn_s_setprio(0);                                                        \
    if ((VM) == 1) { asm volatile("s_waitcnt vmcnt(4)" ::: "memory"); }                   \
    else if ((VM) == 2) { asm volatile("s_waitcnt vmcnt(0)" ::: "memory"); }              \
    __builtin_amdgcn_s_barrier();                                                         \
}

#pragma unroll
    for (int kt = 0; kt < 8; kt += 2) {
        // tile kt (buf0), quadrants 0..3; stage next tiles' halves into just-freed regions
        PHASE(0, 0, 1, { STAGE_A(1, kt + 1, 0); }, 0)
        PHASE(0, 1, 0, { STAGE_A(1, kt + 1, 1); }, 0)
        PHASE(0, 2, 0, { if (kt + 2 < 8) STAGE_B(0, kt + 2, 0); }, 0)
        PHASE(0, 3, 0, { if (kt + 2 < 8) STAGE_B(0, kt + 2, 1); }, (kt + 2 < 8 ? 1 : 2))
        // tile kt+1 (buf1)
        PHASE(1, 0, 1, { if (kt + 2 < 8) STAGE_A(0, kt + 2, 0); }, 0)
        PHASE(1, 1, 0, { if (kt + 2 < 8) STAGE_A(0, kt + 2, 1); }, 0)
        PHASE(1, 2, 0, { if (kt + 3 < 8) STAGE_B(1, kt + 3, 0); }, 0)
        PHASE(1, 3, 0, { if (kt + 3 < 8) STAGE_B(1, kt + 3, 1); }, (kt + 3 < 8 ? 1 : 0))
    }
#undef PHASE
#undef STAGE_A
#undef STAGE_B

    if (MODE == 0) {
        const float* bias = (p == 0) ? b0 : (p == 1) ? b1 : b2;
        ushort_t* outp = (p == 0) ? o0 : (p == 1) ? o1 : o2;
#pragma unroll
        for (int mf = 0; mf < 8; ++mf) {
#pragma unroll
            for (int nf = 0; nf < 4; ++nf) {
                int col = nBlk + wn + nf * 16 + r16;
                int nLocal = col & 511;
                float bv = bias[nLocal];
#pragma unroll
                for (int i = 0; i < 4; ++i) {
                    int row = mBlk + wm + mf * 16 + (kq << 2) + i;
                    float v = acc[mf][nf][i] + bv;
                    if (p == 0) v = __expf(fminf(fmaxf(v, -60.f), 30.f));
                    else if (p == 2) v = 1.f / (1.f + __expf(-v));
                    outp[(size_t)row * 512 + nLocal] = f2bf(v);
                }
            }
        }
    } else {
#pragma unroll
        for (int mf = 0; mf < 8; ++mf) {
#pragma unroll
            for (int nf = 0; nf < 4; ++nf) {
                int col = nBlk + wn + nf * 16 + r16;
                float bv = b0[col];
#pragma unroll
                for (int i = 0; i < 4; ++i) {
                    int row = mBlk + wm + mf * 16 + (kq << 2) + i;
                    float v = (acc[mf][nf][i] + bv) * gamma[row & (TTLEN - 1)];
                    fout[(size_t)row * 512 + col] = v;
                }
            }
        }
    }
}

// ---------------- scan phase A: per-chunk local (S, sum_k), bf16 in ----------------
__global__ void scanA(const ushort_t* __restrict__ kb, const ushort_t* __restrict__ vb,
                      const float* __restrict__ tw, const float* __restrict__ alpha,
                      float* __restrict__ Sloc, float* __restrict__ Kloc) {
    int tid = threadIdx.x;
    int b = blockIdx.x >> 6, j = blockIdx.x & 63;
    int a0 = tid * 2;
    int h = a0 >> 6;
    float r = tw[h * TTLEN + TTLEN - 2];
    int t0 = j * CLEN;
    size_t base = ((size_t)(b * TTLEN + t0)) * 512 + a0;
    const float* al = alpha + h * TTLEN + t0;
    float s0 = 0.f, s1 = 0.f, sk0 = 0.f, sk1 = 0.f;
#pragma unroll 8
    for (int it = 0; it < CLEN; ++it) {
        unsigned int kk = *(const unsigned int*)(kb + base + (size_t)it * 512);
        unsigned int vv = *(const unsigned int*)(vb + base + (size_t)it * 512);
        float kf0 = bf2f(kk & 0xffff), kf1 = bf2f(kk >> 16);
        float vf0 = bf2f(vv & 0xffff), vf1 = bf2f(vv >> 16);
        float av = al[it];
        sk0 += kf0; sk1 += kf1;
        s0 = fmaf(r, s0, av * kf0 * vf0);
        s1 = fmaf(r, s1, av * kf1 * vf1);
    }
    int o = (b * NCH + j) * 512 + a0;
    Sloc[o] = s0; Sloc[o + 1] = s1;
    Kloc[o] = sk0; Kloc[o + 1] = sk1;
}

// ---------------- scan mid: exclusive prefix across chunks ----------------
__global__ void scanMid(const float* __restrict__ tw,
                        const float* __restrict__ Sloc, const float* __restrict__ Kloc,
                        float* __restrict__ Sin, float* __restrict__ Kin) {
    int idx = blockIdx.x * 256 + threadIdx.x;   // 4096 = B*A
    int a = idx & 511, b = idx >> 9;
    int h = a >> 6;
    float r = tw[h * TTLEN + TTLEN - 2];
    float rL = r;
#pragma unroll
    for (int i = 0; i < 5; ++i) rL *= rL;       // r^32
    float cs = 0.f, ck = 0.f;
#pragma unroll
    for (int j = 0; j < NCH; ++j) {
        int o = (b * NCH + j) * 512 + a;
        Sin[o] = cs; Kin[o] = ck;
        cs = fmaf(rL, cs, Sloc[o]);
        ck += Kloc[o];
    }
}

// ---------------- scan phase B: replay with true prefix, emit rwkv bf16 ----------------
__global__ void scanB(const ushort_t* __restrict__ kb, const ushort_t* __restrict__ vb,
                      const ushort_t* __restrict__ rb,
                      const float* __restrict__ tw, const float* __restrict__ alpha,
                      const float* __restrict__ beta,
                      const float* __restrict__ Sin, const float* __restrict__ Kin,
                      ushort_t* __restrict__ rwkv) {
    int tid = threadIdx.x;
    int b = blockIdx.x >> 6, j = blockIdx.x & 63;
    int a0 = tid * 2;
    int h = a0 >> 6;
    float r = tw[h * TTLEN + TTLEN - 2];
    int t0 = j * CLEN;
    size_t base = ((size_t)(b * TTLEN + t0)) * 512 + a0;
    const float* al = alpha + h * TTLEN + t0;
    const float* bt = beta + h * TTLEN + t0;
    int o = (b * NCH + j) * 512 + a0;
    float s0 = Sin[o], s1 = Sin[o + 1], sk0 = Kin[o], sk1 = Kin[o + 1];
#pragma unroll 4
    for (int it = 0; it < CLEN; ++it) {
        unsigned int kk = *(const unsigned int*)(kb + base + (size_t)it * 512);
        unsigned int vv = *(const unsigned int*)(vb + base + (size_t)it * 512);
        unsigned int rr = *(const unsigned int*)(rb + base + (size_t)it * 512);
        float kf0 = bf2f(kk & 0xffff), kf1 = bf2f(kk >> 16);
        float vf0 = bf2f(vv & 0xffff), vf1 = bf2f(vv >> 16);
        float rf0 = bf2f(rr & 0xffff), rf1 = bf2f(rr >> 16);
        float av = al[it], btv = bt[it];
        sk0 += kf0; sk1 += kf1;
        s0 = fmaf(r, s0, av * kf0 * vf0);
        s1 = fmaf(r, s1, av * kf1 * vf1);
        float w0 = btv * s0, w1 = btv * s1;
        unsigned int outw = ((unsigned int)f2bf(rf1 * w1 / sk1) << 16) | f2bf(rf0 * w0 / sk0);
        *(unsigned int*)(rwkv + base + (size_t)it * 512) = outw;
    }
}

extern "C" void kernel_launch(void* const* d_in, const int* in_sizes, int n_in,
                              void* d_out, int out_size, void* d_ws, size_t ws_size,
                              hipStream_t stream) {
    const float* x   = (const float*)d_in[0];
    const float* tw  = (const float*)d_in[1];
    const float* ta  = (const float*)d_in[2];
    const float* tb  = (const float*)d_in[3];
    const float* tg  = (const float*)d_in[4];
    const float* tmk = (const float*)d_in[5];
    const float* tmv = (const float*)d_in[6];
    const float* tmr = (const float*)d_in[7];
    const float* Wk  = (const float*)d_in[8];
    const float* bk  = (const float*)d_in[9];
    const float* Wv  = (const float*)d_in[10];
    const float* bv  = (const float*)d_in[11];
    const float* Wr  = (const float*)d_in[12];
    const float* br  = (const float*)d_in[13];
    const float* Wo  = (const float*)d_in[14];
    const float* bo  = (const float*)d_in[15];

    char* ws = (char*)d_ws;
    ushort_t* Wall = (ushort_t*)(ws + 0);            // [1536][512] bf16 (Wk;Wv;Wr)
    ushort_t* Wob  = (ushort_t*)(ws + 1572864);      // [512][512] bf16
    ushort_t* xk   = (ushort_t*)(ws + 2097152);      // 16.78 MB each
    ushort_t* xv   = (ushort_t*)(ws + 18874368);
    ushort_t* xr   = (ushort_t*)(ws + 35651584);
    ushort_t* kb   = (ushort_t*)(ws + 52428800);
    ushort_t* vb   = (ushort_t*)(ws + 69206016);
    ushort_t* rb   = (ushort_t*)(ws + 85983232);
    ushort_t* rwkv = xk;                             // xk dead after gemm<0>
    float* Sloc = (float*)(ws + 102760448);          // 1 MB each
    float* Kloc = (float*)(ws + 103809024);
    float* Sin  = (float*)(ws + 104857600);
    float* Kin  = (float*)(ws + 105906176);

    convert4<<<1024, 256, 0, stream>>>(Wk, Wv, Wr, Wo, Wall, Wob);
    mix3<<<8192, 256, 0, stream>>>(x, tmk, tmv, tmr, xk, xv, xr);

    // grid: x = M tiles (fast, A-panel locality), y = N tiles
    gemm_8ph<0><<<dim3(64, 6), 512, 0, stream>>>(xk, xv, xr, Wall, bk, bv, br,
                                                 kb, vb, rb, nullptr, nullptr);

    scanA<<<512, 256, 0, stream>>>(kb, vb, tw, ta, Sloc, Kloc);
    scanMid<<<16, 256, 0, stream>>>(tw, Sloc, Kloc, Sin, Kin);
    scanB<<<512, 256, 0, stream>>>(kb, vb, rb, tw, ta, tb, Sin, Kin, rwkv);

    gemm_8ph<1><<<dim3(64, 2), 512, 0, stream>>>(rwkv, nullptr, nullptr, Wob, bo, nullptr,
                                                 nullptr, nullptr, nullptr, nullptr,
                                                 (float*)d_out, tg);
}